// Round 4
// baseline (269.732 us; speedup 1.0000x reference)
//
#include <hip/hip_runtime.h>
#include <hip/hip_bf16.h>
#include <stdint.h>

// Problem constants
#define L_SEQ 2048
#define DI    2048
#define KTOT  8192          // D_CONV * DI
#define BM 128
#define BN 128
#define BK 64
#define KSTEPS (2048 / BK)  // 32 K-steps per tap
#define XPAD_ROWS 2052      // rows -1..2050 of x, zero-padded

typedef __attribute__((ext_vector_type(4))) float f32x4;
typedef __attribute__((ext_vector_type(8))) short bf16x8;

__device__ __forceinline__ unsigned short f2bf(float f) {
  union { float f; unsigned u; } v; v.f = f;
  unsigned r = v.u + 0x7FFFu + ((v.u >> 16) & 1u);   // RNE
  return (unsigned short)(r >> 16);
}

// xpad[r][i]: r==0 or r>=2049 -> 0, else bf16(x[r-1][i]). 4 elems/thread.
__global__ void prep_xpad(const float* __restrict__ x,
                          unsigned short* __restrict__ xpad) {
  const long e = ((long)blockIdx.x * blockDim.x + threadIdx.x) * 4;
  const int row = (int)(e >> 11);
  const int col = (int)(e & 2047);
  ushort4 o;
  if (row >= 1 && row <= L_SEQ) {
    const float4 v = *(const float4*)(x + (long)(row - 1) * DI + col);
    o.x = f2bf(v.x); o.y = f2bf(v.y); o.z = f2bf(v.z); o.w = f2bf(v.w);
  } else {
    o.x = 0; o.y = 0; o.z = 0; o.w = 0;
  }
  *(ushort4*)(xpad + e) = o;
}

// Bt[n][w*2048+i] = bf16(ck[w][i][n]). 64x64 tile per block, one w-slice.
__global__ __launch_bounds__(256) void prep_bt(const float* __restrict__ ck,
                                               unsigned short* __restrict__ bt) {
  __shared__ float tile[64][65];
  const int w  = blockIdx.z;
  const int i0 = blockIdx.x * 64;
  const int n0 = blockIdx.y * 64;
  const int t  = threadIdx.x;
  const float* src = ck + ((long)w * 2048 + i0) * DI + n0;
#pragma unroll
  for (int r = 0; r < 4; ++r) {
    const int row = r * 16 + (t >> 4);
    const int c4  = (t & 15) * 4;
    const float4 v = *(const float4*)(src + (long)row * DI + c4);
    tile[row][c4 + 0] = v.x;
    tile[row][c4 + 1] = v.y;
    tile[row][c4 + 2] = v.z;
    tile[row][c4 + 3] = v.w;
  }
  __syncthreads();
#pragma unroll
  for (int j2 = 0; j2 < 2; ++j2) {
    const int n  = (t >> 3) + j2 * 32;
    const int ic = (t & 7) * 8;
    union { unsigned short u[8]; uint4 v; } o;
#pragma unroll
    for (int j = 0; j < 8; ++j) o.u[j] = f2bf(tile[ic + j][n]);
    *(uint4*)(bt + (long)(n0 + n) * KTOT + (long)w * 2048 + i0 + ic) = o.v;
  }
}

// Split-K by conv tap, T3-minimum 2-phase pipeline:
//   prologue: STAGE(buf0, kt=0); barrier
//   loop:     STAGE(buf^1, kt+1); ds_read buf; setprio(1); 32 MFMA;
//             setprio(0); barrier (drains vmcnt after full MFMA cover); buf^=1
// 128x128 tile, BK=64, dbuf 64KB LDS -> 2 blocks/CU, 4 waves (2x2 of 64x64).
// Grid 1024 (16x16 tiles x 4 taps), bijective XCD swizzle for L2 locality.
__global__ __launch_bounds__(256, 2) void gemm_conv(
    const unsigned short* __restrict__ xpad,
    const unsigned short* __restrict__ bt,
    const float* __restrict__ bias,
    const float* __restrict__ dscale,
    float* __restrict__ out) {
  __shared__ unsigned short As[2][BM * BK];   // 16 KB per buf
  __shared__ unsigned short Bs[2][BN * BK];   // 16 KB per buf

  // bijective XCD swizzle: 1024 blocks = 8 XCDs x 128; each XCD gets one
  // tap's contiguous (bm,bn) range -> A/B panels stay L2-warm.
  const int logical = (blockIdx.x & 7) * 128 + (blockIdx.x >> 3);
  const int w  = logical >> 8;                // conv tap 0..3
  const int bm = (logical >> 4) & 15;
  const int bn = logical & 15;

  const int tid  = threadIdx.x;
  const int lane = tid & 63;
  const int wid  = tid >> 6;
  const int wr   = wid >> 1;
  const int wc   = wid & 1;

  const int sm0 = tid >> 3;                   // staging row base 0..31
  const int sk  = (tid & 7) * 8;              // k offset (8 bf16 = 16B)

  f32x4 acc[4][4];
#pragma unroll
  for (int i = 0; i < 4; ++i)
#pragma unroll
    for (int j = 0; j < 4; ++j)
      acc[i][j] = (f32x4){0.f, 0.f, 0.f, 0.f};

  const int fm = lane & 15;
  const int kq = (lane >> 4) * 8;

  // A rows: t + w - 1 in x == row t + w of xpad
  const unsigned short* gA0 = xpad + (long)(bm * BM + sm0 + w) * DI + sk;
  const unsigned short* gB0 = bt + (long)(bn * BN + sm0) * KTOT + (long)w * 2048 + sk;

  auto stage = [&](int buf, int kt) {
    const unsigned short* gA = gA0 + kt * BK;
    const unsigned short* gB = gB0 + kt * BK;
    unsigned short* lA = &As[buf][tid * 8];
    unsigned short* lB = &Bs[buf][tid * 8];
#pragma unroll
    for (int r = 0; r < 4; ++r) {
      __builtin_amdgcn_global_load_lds(
          (const __attribute__((address_space(1))) void*)(gA + (long)r * 32 * DI),
          (__attribute__((address_space(3))) void*)(lA + r * 2048), 16, 0, 0);
      __builtin_amdgcn_global_load_lds(
          (const __attribute__((address_space(1))) void*)(gB + (long)r * 32 * KTOT),
          (__attribute__((address_space(3))) void*)(lB + r * 2048), 16, 0, 0);
    }
  };

  stage(0, 0);
  __syncthreads();                 // vmcnt(0) drain: tile 0 ready

  int cur = 0;
  for (int kt = 0; kt < KSTEPS; ++kt) {
    if (kt + 1 < KSTEPS) stage(cur ^ 1, kt + 1);   // issue BEFORE compute
    const unsigned short* Ac = &As[cur][0];
    const unsigned short* Bc = &Bs[cur][0];
    bf16x8 av[2][4], bv[2][4];
#pragma unroll
    for (int s = 0; s < 2; ++s)
#pragma unroll
      for (int f = 0; f < 4; ++f) {
        av[s][f] = *(const bf16x8*)&Ac[(wr * 64 + f * 16 + fm) * BK + s * 32 + kq];
        bv[s][f] = *(const bf16x8*)&Bc[(wc * 64 + f * 16 + fm) * BK + s * 32 + kq];
      }
    __builtin_amdgcn_s_setprio(1);
#pragma unroll
    for (int s = 0; s < 2; ++s)
#pragma unroll
      for (int i = 0; i < 4; ++i)
#pragma unroll
        for (int j = 0; j < 4; ++j)
          acc[i][j] = __builtin_amdgcn_mfma_f32_16x16x32_bf16(av[s][i], bv[s][j],
                                                              acc[i][j], 0, 0, 0);
    __builtin_amdgcn_s_setprio(0);
    __syncthreads();               // one vmcnt(0)+barrier per K-step
    cur ^= 1;
  }

  // epilogue: atomic accumulate (acc [+ bias if w==0]) * D into out
  // C/D layout: col = lane&15, row = (lane>>4)*4 + q   [m89/m91 verified]
  const int r0 = bm * BM + wr * 64;
  const int c0 = bn * BN + wc * 64;
#pragma unroll
  for (int j = 0; j < 4; ++j) {
    const int col = c0 + j * 16 + fm;
    const float bb = (w == 0) ? bias[col] : 0.f;
    const float dd = dscale[col];
#pragma unroll
    for (int i = 0; i < 4; ++i) {
      const int row = r0 + i * 16 + (lane >> 4) * 4;
#pragma unroll
      for (int q = 0; q < 4; ++q)
        atomicAdd(&out[(long)(row + q) * DI + col], (acc[i][j][q] + bb) * dd);
    }
  }
}

extern "C" void kernel_launch(void* const* d_in, const int* in_sizes, int n_in,
                              void* d_out, int out_size, void* d_ws, size_t ws_size,
                              hipStream_t stream) {
  // inputs: 0=x, 1=dt_W (dead), 2=dt_b (dead), 3=conv_kernel, 4=conv_b,
  //         5=A_param (dead: scan ys are xt), 6=D_param
  const float* x  = (const float*)d_in[0];
  const float* ck = (const float*)d_in[3];
  const float* cb = (const float*)d_in[4];
  const float* Dp = (const float*)d_in[6];
  float* out = (float*)d_out;

  // ws layout: xpad bf16 (2052*2048 = 8.4 MB), Bt bf16 (2048*8192 = 33.6 MB)
  unsigned short* xpad = (unsigned short*)d_ws;
  unsigned short* Bt =
      (unsigned short*)((char*)d_ws + (size_t)XPAD_ROWS * DI * sizeof(unsigned short));

  prep_xpad<<<(XPAD_ROWS * DI) / (4 * 256), 256, 0, stream>>>(x, xpad);
  prep_bt<<<dim3(32, 32, 4), 256, 0, stream>>>(ck, Bt);
  hipMemsetAsync(d_out, 0, (size_t)out_size * sizeof(float), stream);
  gemm_conv<<<16 * 16 * 4, 256, 0, stream>>>(xpad, Bt, cb, Dp, out);
}

// Round 10
// 247.565 us; speedup vs baseline: 1.0895x; 1.0895x over previous
//
#include <hip/hip_runtime.h>
#include <hip/hip_bf16.h>
#include <stdint.h>

// Problem constants
#define L_SEQ 2048
#define DI    2048
#define KTOT  8192          // D_CONV * DI
#define TM    256           // tile M = tile N
#define TK    64            // K-step
#define NTILE 32            // K-tiles per tap (2048/64)
#define XPAD_ROWS 2052      // rows -1..2050 of x, zero-padded

typedef __attribute__((ext_vector_type(4))) float f32x4;
typedef __attribute__((ext_vector_type(8))) short bf16x8;

#define AS1 __attribute__((address_space(1)))
#define AS3 __attribute__((address_space(3)))

__device__ __forceinline__ unsigned short f2bf(float f) {
  union { float f; unsigned u; } v; v.f = f;
  unsigned r = v.u + 0x7FFFu + ((v.u >> 16) & 1u);   // RNE
  return (unsigned short)(r >> 16);
}

// xpad[r][i]: r==0 or r>=2049 -> 0, else bf16(x[r-1][i]). 4 elems/thread.
__global__ void prep_xpad(const float* __restrict__ x,
                          unsigned short* __restrict__ xpad) {
  const long e = ((long)blockIdx.x * blockDim.x + threadIdx.x) * 4;
  const int row = (int)(e >> 11);
  const int col = (int)(e & 2047);
  ushort4 o;
  if (row >= 1 && row <= L_SEQ) {
    const float4 v = *(const float4*)(x + (long)(row - 1) * DI + col);
    o.x = f2bf(v.x); o.y = f2bf(v.y); o.z = f2bf(v.z); o.w = f2bf(v.w);
  } else {
    o.x = 0; o.y = 0; o.z = 0; o.w = 0;
  }
  *(ushort4*)(xpad + e) = o;
}

// Bt[n][w*2048+i] = bf16(ck[w][i][n]). 64x64 tile per block, one w-slice.
__global__ __launch_bounds__(256) void prep_bt(const float* __restrict__ ck,
                                               unsigned short* __restrict__ bt) {
  __shared__ float tile[64][65];
  const int w  = blockIdx.z;
  const int i0 = blockIdx.x * 64;
  const int n0 = blockIdx.y * 64;
  const int t  = threadIdx.x;
  const float* src = ck + ((long)w * 2048 + i0) * DI + n0;
#pragma unroll
  for (int r = 0; r < 4; ++r) {
    const int row = r * 16 + (t >> 4);
    const int c4  = (t & 15) * 4;
    const float4 v = *(const float4*)(src + (long)row * DI + c4);
    tile[row][c4 + 0] = v.x;
    tile[row][c4 + 1] = v.y;
    tile[row][c4 + 2] = v.z;
    tile[row][c4 + 3] = v.w;
  }
  __syncthreads();
#pragma unroll
  for (int j2 = 0; j2 < 2; ++j2) {
    const int n  = (t >> 3) + j2 * 32;
    const int ic = (t & 7) * 8;
    union { unsigned short u[8]; uint4 v; } o;
#pragma unroll
    for (int j = 0; j < 8; ++j) o.u[j] = f2bf(tile[ic + j][n]);
    *(uint4*)(bt + (long)(n0 + n) * KTOT + (long)w * 2048 + i0 + ic) = o.v;
  }
}

// 256x256 tile, split-K by conv tap. 8 waves (2M x 4N), 128KB LDS (2 bufs),
// 8-phase schedule: burst-stage 8 gload_lds per K-tile, counted vmcnt(8)
// (never 0 in steady state), raw s_barrier, per-phase {ds_read, barrier,
// lgkmcnt(0), setprio, 16 MFMA, setprio, barrier}. T2 XOR swizzle via
// pre-swizzled global source (gload_lds dest linear; rule #21).
// LDS chunk map: 16B chunk (row, k0) stored at slot row*8 + (k0 ^ (row&7)).
__global__ __launch_bounds__(512, 2) void gemm_conv(
    const unsigned short* __restrict__ xpad,
    const unsigned short* __restrict__ bt,
    const float* __restrict__ bias,
    const float* __restrict__ dscale,
    float* __restrict__ out) {
  __shared__ unsigned short lds[2][2][TM * TK];   // [buf][A/B][.] = 128 KB

  const int tid  = threadIdx.x;
  const int lane = tid & 63;
  const int wave = tid >> 6;
  const int wr   = wave >> 2;          // 0..1 : 128-row band
  const int wc   = wave & 3;           // 0..3 : 64-col band
  const int fm   = lane & 15;
  const int g    = lane >> 4;          // 0..3

  // XCD swizzle (bijective, 256 = 8 XCDs x 32): one tap stays per XCD.
  const int l  = ((int)blockIdx.x & 7) * 32 + ((int)blockIdx.x >> 3);
  const int w  = l >> 6;               // conv tap 0..3
  const int bm = (l >> 3) & 7;
  const int bn = l & 7;

  const long rowA0 = (long)bm * TM + w;     // xpad row base (t + w)
  const long colB0 = (long)bn * TM;         // Bt row base
  const long wk    = (long)w * 2048;        // tap's k-slice in Bt

  // ds_read byte bases: addr = base + m*2048 + xorb[s]  (offset-immediate friendly)
  const int baseA = (wr * 128 + fm) * 128;
  const int baseB = (wc * 64 + fm) * 128;
  int xorb[2];
  xorb[0] = ((0 + g) ^ (fm & 7)) * 16;
  xorb[1] = ((4 + g) ^ (fm & 7)) * 16;

  f32x4 acc[8][4];
#pragma unroll
  for (int m = 0; m < 8; ++m)
#pragma unroll
    for (int n = 0; n < 4; ++n)
      acc[m][n] = (f32x4){0.f, 0.f, 0.f, 0.f};

  // Burst-stage one K-tile (A+B, 8 gload_lds/thread). Source pre-swizzled:
  // thread's linear LDS slot s holds global chunk (row = s>>3, k0 = (s&7)^(row&7)).
  auto stageT = [&](int buf, int kt) {
    const long kb = (long)kt * TK;
    unsigned short* lA = &lds[buf][0][0];
    unsigned short* lB = &lds[buf][1][0];
#pragma unroll
    for (int r = 0; r < 4; ++r) {
      const int s   = r * 512 + tid;
      const int row = s >> 3;
      const int k0  = (s & 7) ^ (row & 7);
      const unsigned short* gA = xpad + (rowA0 + row) * DI + kb + k0 * 8;
      __builtin_amdgcn_global_load_lds((const AS1 void*)gA,
                                       (AS3 void*)(lA + (size_t)s * 8), 16, 0, 0);
      const unsigned short* gB = bt + (colB0 + row) * KTOT + wk + kb + k0 * 8;
      __builtin_amdgcn_global_load_lds((const AS1 void*)gB,
                                       (AS3 void*)(lB + (size_t)s * 8), 16, 0, 0);
    }
  };

  // Consume one staged K-tile: 4 phases, phase q does m-pair {2q,2q+1} x n0..3 x s0..1.
  auto consume = [&](int buf) {
    const char* Ab = (const char*)&lds[buf][0][0];
    const char* Bb = (const char*)&lds[buf][1][0];
    bf16x8 bv[4][2];
#pragma unroll
    for (int q = 0; q < 4; ++q) {
      bf16x8 av[2][2];
      if (q == 0) {
#pragma unroll
        for (int n = 0; n < 4; ++n)
#pragma unroll
          for (int s = 0; s < 2; ++s)
            bv[n][s] = *(const bf16x8*)(Bb + baseB + n * 2048 + xorb[s]);
      }
#pragma unroll
      for (int mm = 0; mm < 2; ++mm)
#pragma unroll
        for (int s = 0; s < 2; ++s)
          av[mm][s] = *(const bf16x8*)(Ab + baseA + (q * 2 + mm) * 2048 + xorb[s]);
      __builtin_amdgcn_s_barrier();
      asm volatile("s_waitcnt lgkmcnt(0)" ::: "memory");
      __builtin_amdgcn_sched_barrier(0);   // rule 18: keep MFMA below the wait
      __builtin_amdgcn_s_setprio(1);
#pragma unroll
      for (int s = 0; s < 2; ++s)
#pragma unroll
        for (int mm = 0; mm < 2; ++mm)
#pragma unroll
          for (int n = 0; n < 4; ++n)
            acc[q * 2 + mm][n] = __builtin_amdgcn_mfma_f32_16x16x32_bf16(
                av[mm][s], bv[n][s], acc[q * 2 + mm][n], 0, 0, 0);
      __builtin_amdgcn_s_setprio(0);
      __builtin_amdgcn_sched_barrier(0);
      __builtin_amdgcn_s_barrier();        // buf's reads retired for all waves
    }
  };

  // Ledger: entering iter i, tile 2i's 8 loads are the oldest outstanding.
  // p0: stage(2i+1) -> 16 out; vmcnt(8) waits tile 2i; barrier; consume buf0.
  // p4: stage(2i+2) -> 16 out; vmcnt(8) waits tile 2i+1; barrier; consume buf1.
  stageT(0, 0);
  for (int it = 0; it < 16; ++it) {
    stageT(1, 2 * it + 1);
    asm volatile("s_waitcnt vmcnt(8)" ::: "memory");
    __builtin_amdgcn_s_barrier();          // tile 2it ready (all waves)
    consume(0);
    if (it < 15) {
      stageT(0, 2 * it + 2);
      asm volatile("s_waitcnt vmcnt(8)" ::: "memory");
    } else {
      asm volatile("s_waitcnt vmcnt(0)" ::: "memory");  // tail only
    }
    __builtin_amdgcn_s_barrier();          // tile 2it+1 ready
    consume(1);
  }

  // epilogue: atomic accumulate (acc [+ bias if w==0]) * D into out
  // C/D layout: col = lane&15, row = (lane>>4)*4 + q   [m89/m91 verified]
#pragma unroll
  for (int m = 0; m < 8; ++m) {
    const long row = (long)bm * TM + wr * 128 + m * 16 + g * 4;
#pragma unroll
    for (int n = 0; n < 4; ++n) {
      const int col = bn * TM + wc * 64 + n * 16 + fm;
      const float bb = (w == 0) ? bias[col] : 0.f;
      const float dd = dscale[col];
#pragma unroll
      for (int qq = 0; qq < 4; ++qq)
        atomicAdd(&out[(row + qq) * DI + col], (acc[m][n][qq] + bb) * dd);
    }
  }
}

extern "C" void kernel_launch(void* const* d_in, const int* in_sizes, int n_in,
                              void* d_out, int out_size, void* d_ws, size_t ws_size,
                              hipStream_t stream) {
  // inputs: 0=x, 1=dt_W (dead), 2=dt_b (dead), 3=conv_kernel, 4=conv_b,
  //         5=A_param (dead: scan ys are xt), 6=D_param
  const float* x  = (const float*)d_in[0];
  const float* ck = (const float*)d_in[3];
  const float* cb = (const float*)d_in[4];
  const float* Dp = (const float*)d_in[6];
  float* out = (float*)d_out;

  // ws layout: xpad bf16 (2052*2048 = 8.4 MB), Bt bf16 (2048*8192 = 33.6 MB)
  unsigned short* xpad = (unsigned short*)d_ws;
  unsigned short* Bt =
      (unsigned short*)((char*)d_ws + (size_t)XPAD_ROWS * DI * sizeof(unsigned short));

  prep_xpad<<<(XPAD_ROWS * DI) / (4 * 256), 256, 0, stream>>>(x, xpad);
  prep_bt<<<dim3(32, 32, 4), 256, 0, stream>>>(ck, Bt);
  hipMemsetAsync(d_out, 0, (size_t)out_size * sizeof(float), stream);
  gemm_conv<<<8 * 8 * 4, 512, 0, stream>>>(xpad, Bt, cb, Dp, out);
}

// Round 13
// 244.862 us; speedup vs baseline: 1.1016x; 1.0110x over previous
//
#include <hip/hip_runtime.h>
#include <hip/hip_bf16.h>
#include <stdint.h>

// Problem constants
#define L_SEQ 2048
#define DI    2048
#define KTOT  8192          // D_CONV * DI
#define TM    256           // tile M = tile N
#define TK    64            // K-step
#define XPAD_ROWS 2052      // rows -1..2050 of x, zero-padded

typedef __attribute__((ext_vector_type(4))) float f32x4;
typedef __attribute__((ext_vector_type(8))) short bf16x8;

#define AS1 __attribute__((address_space(1)))
#define AS3 __attribute__((address_space(3)))

__device__ __forceinline__ unsigned short f2bf(float f) {
  union { float f; unsigned u; } v; v.f = f;
  unsigned r = v.u + 0x7FFFu + ((v.u >> 16) & 1u);   // RNE
  return (unsigned short)(r >> 16);
}

// xpad[r][i]: r==0 or r>=2049 -> 0, else bf16(x[r-1][i]). 4 elems/thread.
__global__ void prep_xpad(const float* __restrict__ x,
                          unsigned short* __restrict__ xpad) {
  const long e = ((long)blockIdx.x * blockDim.x + threadIdx.x) * 4;
  const int row = (int)(e >> 11);
  const int col = (int)(e & 2047);
  ushort4 o;
  if (row >= 1 && row <= L_SEQ) {
    const float4 v = *(const float4*)(x + (long)(row - 1) * DI + col);
    o.x = f2bf(v.x); o.y = f2bf(v.y); o.z = f2bf(v.z); o.w = f2bf(v.w);
  } else {
    o.x = 0; o.y = 0; o.z = 0; o.w = 0;
  }
  *(ushort4*)(xpad + e) = o;
}

// Bt[n][w*2048+i] = bf16(ck[w][i][n]). 64x64 tile per block, one w-slice.
__global__ __launch_bounds__(256) void prep_bt(const float* __restrict__ ck,
                                               unsigned short* __restrict__ bt) {
  __shared__ float tile[64][65];
  const int w  = blockIdx.z;
  const int i0 = blockIdx.x * 64;
  const int n0 = blockIdx.y * 64;
  const int t  = threadIdx.x;
  const float* src = ck + ((long)w * 2048 + i0) * DI + n0;
#pragma unroll
  for (int r = 0; r < 4; ++r) {
    const int row = r * 16 + (t >> 4);
    const int c4  = (t & 15) * 4;
    const float4 v = *(const float4*)(src + (long)row * DI + c4);
    tile[row][c4 + 0] = v.x;
    tile[row][c4 + 1] = v.y;
    tile[row][c4 + 2] = v.z;
    tile[row][c4 + 3] = v.w;
  }
  __syncthreads();
#pragma unroll
  for (int j2 = 0; j2 < 2; ++j2) {
    const int n  = (t >> 3) + j2 * 32;
    const int ic = (t & 7) * 8;
    union { unsigned short u[8]; uint4 v; } o;
#pragma unroll
    for (int j = 0; j < 8; ++j) o.u[j] = f2bf(tile[ic + j][n]);
    *(uint4*)(bt + (long)(n0 + n) * KTOT + (long)w * 2048 + i0 + ic) = o.v;
  }
}

// 256x256 tile, split-K by conv tap. 8 waves (2M x 4N), 128KB LDS (2 bufs).
// Sync-minimal pipeline: burst-stage 8 gload_lds/thread per K-tile, counted
// vmcnt(8) (never 0 in steady state), only TWO raw s_barriers per K-tile
// (ready + done). Inside consume: plain ds_reads + MFMA, compiler emits
// fine-grained lgkmcnt; waves drift to overlap each other's MFMA/LDS/VMEM.
// T2 XOR swizzle via pre-swizzled global source (gload_lds dest linear).
// LDS chunk map: 16B chunk (row, k0) stored at slot row*8 + (k0 ^ (row&7)).
__global__ __launch_bounds__(512, 2) void gemm_conv(
    const unsigned short* __restrict__ xpad,
    const unsigned short* __restrict__ bt,
    const float* __restrict__ bias,
    const float* __restrict__ dscale,
    float* __restrict__ out) {
  __shared__ unsigned short lds[2][2][TM * TK];   // [buf][A/B][.] = 128 KB

  const int tid  = threadIdx.x;
  const int lane = tid & 63;
  const int wave = tid >> 6;
  const int wr   = wave >> 2;          // 0..1 : 128-row band
  const int wc   = wave & 3;           // 0..3 : 64-col band
  const int fm   = lane & 15;
  const int g    = lane >> 4;          // 0..3

  // XCD swizzle (bijective, 256 = 8 XCDs x 32): one tap stays per XCD.
  const int l  = ((int)blockIdx.x & 7) * 32 + ((int)blockIdx.x >> 3);
  const int w  = l >> 6;               // conv tap 0..3
  const int bm = (l >> 3) & 7;
  const int bn = l & 7;

  const long rowA0 = (long)bm * TM + w;     // xpad row base (t + w)
  const long colB0 = (long)bn * TM;         // Bt row base
  const long wk    = (long)w * 2048;        // tap's k-slice in Bt

  // ds_read byte bases: addr = base + m*2048 + xorb[s]
  const int baseA = (wr * 128 + fm) * 128;
  const int baseB = (wc * 64 + fm) * 128;
  int xorb[2];
  xorb[0] = ((0 + g) ^ (fm & 7)) * 16;
  xorb[1] = ((4 + g) ^ (fm & 7)) * 16;

  f32x4 acc[8][4];
#pragma unroll
  for (int m = 0; m < 8; ++m)
#pragma unroll
    for (int n = 0; n < 4; ++n)
      acc[m][n] = (f32x4){0.f, 0.f, 0.f, 0.f};

  // Burst-stage one K-tile (A+B, 8 gload_lds/thread). Source pre-swizzled:
  // thread's linear LDS slot s holds global chunk (row = s>>3, k0 = (s&7)^(row&7)).
  auto stageT = [&](int buf, int kt) {
    const long kb = (long)kt * TK;
    unsigned short* lA = &lds[buf][0][0];
    unsigned short* lB = &lds[buf][1][0];
#pragma unroll
    for (int r = 0; r < 4; ++r) {
      const int s   = r * 512 + tid;
      const int row = s >> 3;
      const int k0  = (s & 7) ^ (row & 7);
      const unsigned short* gA = xpad + (rowA0 + row) * DI + kb + k0 * 8;
      __builtin_amdgcn_global_load_lds((const AS1 void*)gA,
                                       (AS3 void*)(lA + (size_t)s * 8), 16, 0, 0);
      const unsigned short* gB = bt + (colB0 + row) * KTOT + wk + kb + k0 * 8;
      __builtin_amdgcn_global_load_lds((const AS1 void*)gB,
                                       (AS3 void*)(lB + (size_t)s * 8), 16, 0, 0);
    }
  };

  // Consume one staged K-tile: no internal barriers; compiler schedules
  // ds_read <-> MFMA with its own fine-grained lgkmcnt waits.
  auto consume = [&](int buf) {
    const char* Ab = (const char*)&lds[buf][0][0];
    const char* Bb = (const char*)&lds[buf][1][0];
    bf16x8 bv[4][2];
#pragma unroll
    for (int n = 0; n < 4; ++n)
#pragma unroll
      for (int s = 0; s < 2; ++s)
        bv[n][s] = *(const bf16x8*)(Bb + baseB + n * 2048 + xorb[s]);
    __builtin_amdgcn_s_setprio(1);
#pragma unroll
    for (int q = 0; q < 4; ++q) {
      bf16x8 av[2][2];
#pragma unroll
      for (int mm = 0; mm < 2; ++mm)
#pragma unroll
        for (int s = 0; s < 2; ++s)
          av[mm][s] = *(const bf16x8*)(Ab + baseA + (q * 2 + mm) * 2048 + xorb[s]);
#pragma unroll
      for (int s = 0; s < 2; ++s)
#pragma unroll
        for (int mm = 0; mm < 2; ++mm)
#pragma unroll
          for (int n = 0; n < 4; ++n)
            acc[q * 2 + mm][n] = __builtin_amdgcn_mfma_f32_16x16x32_bf16(
                av[mm][s], bv[n][s], acc[q * 2 + mm][n], 0, 0, 0);
    }
    __builtin_amdgcn_s_setprio(0);
  };

  // Ledger (per wave): entering iter i, tile 2i's 8 loads are oldest outstanding.
  // stage(2i+1) -> 16 out; vmcnt(8) waits tile 2i; ready-barrier; consume buf0;
  // done-barrier (all waves' buf0 reads retired: each read feeds an MFMA before
  // the barrier, so the compiler's lgkmcnt precedes it); then stage(2i+2) may
  // overwrite buf0. Fence after each barrier stops ds_read hoisting above it.
  stageT(0, 0);
  for (int it = 0; it < 16; ++it) {
    stageT(1, 2 * it + 1);
    asm volatile("s_waitcnt vmcnt(8)" ::: "memory");
    __builtin_amdgcn_s_barrier();          // tile 2it ready (all waves)
    asm volatile("" ::: "memory");
    consume(0);
    __builtin_amdgcn_s_barrier();          // buf0 reads done (all waves)
    asm volatile("" ::: "memory");
    if (it < 15) {
      stageT(0, 2 * it + 2);
      asm volatile("s_waitcnt vmcnt(8)" ::: "memory");
    } else {
      asm volatile("s_waitcnt vmcnt(0)" ::: "memory");  // tail only
    }
    __builtin_amdgcn_s_barrier();          // tile 2it+1 ready
    asm volatile("" ::: "memory");
    consume(1);
    __builtin_amdgcn_s_barrier();          // buf1 reads done
    asm volatile("" ::: "memory");
  }

  // epilogue: atomic accumulate (acc [+ bias if w==0]) * D into out
  // C/D layout: col = lane&15, row = (lane>>4)*4 + q   [m89/m91 verified]
#pragma unroll
  for (int m = 0; m < 8; ++m) {
    const long row = (long)bm * TM + wr * 128 + m * 16 + g * 4;
#pragma unroll
    for (int n = 0; n < 4; ++n) {
      const int col = bn * TM + wc * 64 + n * 16 + fm;
      const float bb = (w == 0) ? bias[col] : 0.f;
      const float dd = dscale[col];
#pragma unroll
      for (int qq = 0; qq < 4; ++qq)
        atomicAdd(&out[(row + qq) * DI + col], (acc[m][n][qq] + bb) * dd);
    }
  }
}

extern "C" void kernel_launch(void* const* d_in, const int* in_sizes, int n_in,
                              void* d_out, int out_size, void* d_ws, size_t ws_size,
                              hipStream_t stream) {
  // inputs: 0=x, 1=dt_W (dead), 2=dt_b (dead), 3=conv_kernel, 4=conv_b,
  //         5=A_param (dead: scan ys are xt), 6=D_param
  const float* x  = (const float*)d_in[0];
  const float* ck = (const float*)d_in[3];
  const float* cb = (const float*)d_in[4];
  const float* Dp = (const float*)d_in[6];
  float* out = (float*)d_out;

  // ws layout: xpad bf16 (2052*2048 = 8.4 MB), Bt bf16 (2048*8192 = 33.6 MB)
  unsigned short* xpad = (unsigned short*)d_ws;
  unsigned short* Bt =
      (unsigned short*)((char*)d_ws + (size_t)XPAD_ROWS * DI * sizeof(unsigned short));

  prep_xpad<<<(XPAD_ROWS * DI) / (4 * 256), 256, 0, stream>>>(x, xpad);
  prep_bt<<<dim3(32, 32, 4), 256, 0, stream>>>(ck, Bt);
  hipMemsetAsync(d_out, 0, (size_t)out_size * sizeof(float), stream);
  gemm_conv<<<8 * 8 * 4, 512, 0, stream>>>(xpad, Bt, cb, Dp, out);
}